// Round 8
// baseline (104.036 us; speedup 1.0000x reference)
//
#include <hip/hip_runtime.h>
#include <cstdint>
#include <cstddef>

typedef __attribute__((ext_vector_type(8))) __bf16 bf16x8;
typedef __attribute__((ext_vector_type(2))) __bf16 bf16x2;
typedef __attribute__((ext_vector_type(4))) float f32x4;
typedef __attribute__((ext_vector_type(4))) unsigned int u32x4;

#define LOG2E 1.44269504088896340736f

constexpr int N_ = 8;
constexpr int S_ = 2048;
constexpr int D_ = 64;
constexpr int V_ = 64;
constexpr int TQ = 16;   // queries per block (one MFMA tile)
constexpr int CK = 32;   // keys per chunk (one 32-key MFMA K-step)
constexpr int NW = 4;    // waves per block (K-split)

// Opaque 16B global load, SGPR base + 32-bit VGPR offset (1 addr VGPR/lane).
#define GLDS(d, off, base, OFF) \
    asm volatile("global_load_dwordx4 %0, %1, %2 offset:" OFF \
                 : "=&v"(d) : "v"(off), "s"(base))
// Counted VMEM wait + scheduler fence (rule #18: reg-only MFMA can be hoisted
// past an asm waitcnt unless a sched_barrier follows).
#define WAITV(N) do { asm volatile("s_waitcnt vmcnt(" #N ")" ::: "memory"); \
                      __builtin_amdgcn_sched_barrier(0); } while (0)

__device__ __forceinline__ ushort f2bf(float x) {      // fp32 -> bf16 RNE
    uint u = __builtin_bit_cast(uint, x);
    return (ushort)((u + 0x7FFFu + ((u >> 16) & 1u)) >> 16);
}
__device__ __forceinline__ bf16x8 bc8(const u32x4& q) {
    return __builtin_bit_cast(bf16x8, q);
}
__device__ __forceinline__ bf16x8 cvt8(const float* p, float sc) {
    f32x4 a = *reinterpret_cast<const f32x4*>(p);
    f32x4 b = *reinterpret_cast<const f32x4*>(p + 4);
    bf16x8 r;
#pragma unroll
    for (int j = 0; j < 4; j++) { r[j] = (__bf16)(a[j] * sc); r[j + 4] = (__bf16)(b[j] * sc); }
    return r;
}
__device__ __forceinline__ uint pk2(float lo, float hi) {   // 2xf32 -> packed bf16x2
    bf16x2 t; t[0] = (__bf16)lo; t[1] = (__bf16)hi;
    return __builtin_bit_cast(uint, t);
}

// prefix_len dtype sniff (int64 iff hi-words all zero; values < 2048).
__device__ __forceinline__ int load_prefix(const int* plen, int n) {
    bool is64 = ((plen[1] | plen[3] | plen[5] | plen[7]) == 0);
    return is64 ? plen[2 * n] : plen[n];
}

// fp32 Q/K/V -> bf16. Qb pre-scaled by 0.125*LOG2E (exp2-domain scores).
// VT[n][s>>5][v][s&31]: V transposed, tiled by 32-key chunk so the attn
// kernel's 4 V loads per chunk fit 13-bit asm immediates {0,1024,2048,3072}.
__global__ void prep_kernel(const float* __restrict__ Q, const float* __restrict__ K,
                            const float* __restrict__ V, ushort* __restrict__ Qb,
                            ushort* __restrict__ Kb, ushort* __restrict__ VTb) {
    const float QS = 0.125f * LOG2E;
    const int i4 = (blockIdx.x * 256 + threadIdx.x) * 4;   // over N*S*64 = 2^20 elems
    f32x4 q = *reinterpret_cast<const f32x4*>(Q + i4);
    f32x4 k = *reinterpret_cast<const f32x4*>(K + i4);
    f32x4 v = *reinterpret_cast<const f32x4*>(V + i4);
    ushort4 qo, ko;
    qo.x = f2bf(q[0] * QS); qo.y = f2bf(q[1] * QS); qo.z = f2bf(q[2] * QS); qo.w = f2bf(q[3] * QS);
    ko.x = f2bf(k[0]); ko.y = f2bf(k[1]); ko.z = f2bf(k[2]); ko.w = f2bf(k[3]);
    *reinterpret_cast<ushort4*>(Qb + i4) = qo;
    *reinterpret_cast<ushort4*>(Kb + i4) = ko;
    const int vd = i4 & (V_ - 1);
    const int s  = (i4 >> 6) & (S_ - 1);
    const int n  = i4 >> 17;
    const size_t base = ((size_t)n * 64 + (s >> 5)) * 2048 + (s & 31);
#pragma unroll
    for (int j = 0; j < 4; j++)
        VTb[base + (size_t)(vd + j) * 32] = f2bf(v[j]);
}

// Swapped-QK flash attention, TQ=16, 4-wave K-split, 32-key chunks.
// Register double-buffered asm-load pipeline (distance 1), SLIM registers:
// bufs 2x8xu32x4 = 64 VGPRs, SGPR-base loads -> total ~120 VGPRs ->
// __launch_bounds__(256,4) -> 4 waves/SIMD, all 1024 blocks resident
// (16 waves/CU TLP; R6's 200-VGPR/512-block config was stuck at 2/SIMD).
// Split counted waits: WAITV(12) K ready -> QK+exp; WAITV(8) V ready -> PV;
// refill; never drain to 0 in the steady loop.
// Fixed-exponent softmax: p = 2^score unnormalized (bounded ~2^17, safe).
//   S^T = mfma(A=K_perm, B=Q): lane = query l16, keys quad*8..+7
//   O^T = mfma(A=V^T, B=P^T): P lands in B-fragment order -> zero transpose.
template <bool WS>
__global__ __launch_bounds__(256, 4) void attn_kernel(
    const void* __restrict__ Qp, const void* __restrict__ Kp,
    const void* __restrict__ Vp, const ushort* __restrict__ VTb,
    const int* __restrict__ plen, float* __restrict__ outm)
{
    __shared__ float obuf[NW][TQ][V_ + 1];   // +1: merge-stage bank spread
    __shared__ float lbuf[NW][TQ];

    const int n    = blockIdx.y;             // n spread across XCDs (x fastest)
    const int q0   = blockIdx.x * TQ;
    const int tid  = threadIdx.x;
    const int w    = tid >> 6;
    const int lane = tid & 63;
    const int quad = lane >> 4;
    const int l16  = lane & 15;
    const int prefix = load_prefix(plen, n);
    const int qrow = q0 + l16;

    // A-row permutation for QK: A row x holds key kb + 8*(x>>2) + (x&3)
    const int krow = ((l16 >> 2) << 3) + (l16 & 3);

    // Q B-fragment: lane holds Q[qrow][quad*8 + (0..7)] (+32 for qf1)
    bf16x8 qf0, qf1;
    if (WS) {
        const ushort* qptr = (const ushort*)Qp + ((size_t)(n * S_ + qrow)) * D_ + quad * 8;
        uint4 u0 = *reinterpret_cast<const uint4*>(qptr);
        uint4 u1 = *reinterpret_cast<const uint4*>(qptr + 32);
        qf0 = __builtin_bit_cast(bf16x8, u0); qf1 = __builtin_bit_cast(bf16x8, u1);
    } else {
        const float* qptr = (const float*)Qp + ((size_t)(n * S_ + qrow)) * D_ + quad * 8;
        qf0 = cvt8(qptr, 0.125f * LOG2E); qf1 = cvt8(qptr + 32, 0.125f * LOG2E);
    }
    // Materialize Q now: the compiler's vmcnt wait for these loads lands HERE,
    // before our asm prefetches -- keeps our counted vmcnt bookkeeping exact.
    asm volatile("" : "+v"(qf0), "+v"(qf1));

    f32x4 oacc[4];
#pragma unroll
    for (int vb = 0; vb < 4; vb++) oacc[vb] = (f32x4){0.f, 0.f, 0.f, 0.f};
    float l_r = 0.f;

    const float* Kf = (const float*)Kp + (size_t)n * S_ * D_;
    const float* Vf = (const float*)Vp + (size_t)n * S_ * V_;

    // Uniform SGPR bases (per-n) + per-lane 32-bit voffsets (chunk 0).
    const ushort* Kbb = (const ushort*)Kp + (size_t)n * S_ * D_;
    const ushort* VTn = VTb + (size_t)n * 64 * 2048;
    const uint vk0 = (uint)(krow * 128 + quad * 16);
    const uint vv0 = (uint)(l16 * 64 + quad * 16);

    // Issue one chunk's 8 loads (K: 4, V: 4) into buffer f.
    auto issueKV = [&](u32x4* f, int c) {
        const uint ko = vk0 + (uint)c * 4096u;   // 32 keys * 128 B
        const uint vo = vv0 + (uint)c * 4096u;   // 32 keys * 64 v * 2 B
        GLDS(f[0], ko, Kbb, "0");    GLDS(f[1], ko, Kbb, "64");
        GLDS(f[2], ko, Kbb, "512");  GLDS(f[3], ko, Kbb, "576");
        GLDS(f[4], vo, VTn, "0");    GLDS(f[5], vo, VTn, "1024");
        GLDS(f[6], vo, VTn, "2048"); GLDS(f[7], vo, VTn, "3072");
    };

    // Chunk compute. If wait8: K already arrived (WAITV(12) by caller);
    // WAITV(8) just before PV (V arrival; next chunk stays in flight).
    auto computeChunk = [&](const u32x4* f, int kb, bool masked, bool wait8) {
        const f32x4 zero = (f32x4){0.f, 0.f, 0.f, 0.f};
        f32x4 s0 = __builtin_amdgcn_mfma_f32_16x16x32_bf16(bc8(f[0]), qf0, zero, 0, 0, 0);
        s0 = __builtin_amdgcn_mfma_f32_16x16x32_bf16(bc8(f[1]), qf1, s0, 0, 0, 0);
        f32x4 s1 = __builtin_amdgcn_mfma_f32_16x16x32_bf16(bc8(f[2]), qf0, zero, 0, 0, 0);
        s1 = __builtin_amdgcn_mfma_f32_16x16x32_bf16(bc8(f[3]), qf1, s1, 0, 0, 0);
        // lane: s0[r] = key kb+8*quad+r, s1[r] = +4; exp2-domain scores
        if (masked) {
#pragma unroll
            for (int r = 0; r < 4; r++) {
                const int k0 = kb + 8 * quad + r;
                s0[r] = (k0     < prefix || k0     == qrow) ? s0[r] : -1e30f;
                s1[r] = (k0 + 4 < prefix || k0 + 4 == qrow) ? s1[r] : -1e30f;
            }
        }
        float p0[4], p1[4];
#pragma unroll
        for (int r = 0; r < 4; r++) {
            p0[r] = __builtin_amdgcn_exp2f(s0[r]);
            p1[r] = __builtin_amdgcn_exp2f(s1[r]);
        }
        l_r += ((p0[0] + p0[1]) + (p0[2] + p0[3])) + ((p1[0] + p1[1]) + (p1[2] + p1[3]));
        uint4 pw;
        pw.x = pk2(p0[0], p0[1]); pw.y = pk2(p0[2], p0[3]);
        pw.z = pk2(p1[0], p1[1]); pw.w = pk2(p1[2], p1[3]);
        const bf16x8 pB = __builtin_bit_cast(bf16x8, pw);
        if (wait8) WAITV(8);                 // V arrived (next chunk in flight)
#pragma unroll
        for (int vb = 0; vb < 4; vb++)
            oacc[vb] = __builtin_amdgcn_mfma_f32_16x16x32_bf16(bc8(f[4 + vb]), pB, oacc[vb], 0, 0, 0);
    };

    const int nFull = prefix >> 5;                 // fully-valid 32-key chunks
    const int nPC   = (prefix + CK - 1) >> 5;
    const int dc    = q0 >> 5;                     // chunk holding the diagonal

    if (WS) {
        u32x4 bufA[8], bufB[8];
        int c = w;
        if (c < nFull) {
            issueKV(bufA, c);
            int c1 = c + NW;
            if (c1 >= nFull) {
                WAITV(0); computeChunk(bufA, c * CK, false, false);
            } else {
                issueKV(bufB, c1);
                for (;;) {
                    int c2 = c1 + NW;
                    if (c2 >= nFull) {
                        WAITV(8); computeChunk(bufA, c * CK, false, false);
                        WAITV(0); computeChunk(bufB, c1 * CK, false, false);
                        break;
                    }
                    WAITV(12);                                  // A.K arrived
                    computeChunk(bufA, c * CK, false, true);    // QK..WAITV(8)..PV
                    issueKV(bufA, c2);                          // refill A
                    c = c1; c1 = c2; c2 = c1 + NW;
                    if (c2 >= nFull) {
                        WAITV(8); computeChunk(bufB, c * CK, false, false);
                        WAITV(0); computeChunk(bufA, c1 * CK, false, false);
                        break;
                    }
                    WAITV(12);                                  // B.K arrived
                    computeChunk(bufB, c * CK, false, true);
                    issueKV(bufB, c2);                          // refill B
                    c = c1; c1 = c2;
                }
            }
        }
        if (nPC > nFull && (nFull & (NW - 1)) == w) {   // masked boundary
            issueKV(bufA, nFull); WAITV(0); computeChunk(bufA, nFull * CK, true, false);
        }
        if (dc >= nPC && (dc & (NW - 1)) == w) {        // pure diagonal
            issueKV(bufA, dc); WAITV(0); computeChunk(bufA, dc * CK, true, false);
        }
    } else {
        // fallback (fp32 inputs): unpipelined; separate template instantiation,
        // so its register pressure cannot affect the WS kernel.
        auto computeNW = [&](int kb, bool masked) {
            u32x4 f[8];
            const float* kp = Kf + (size_t)(kb + krow) * D_ + quad * 8;
            f[0] = __builtin_bit_cast(u32x4, cvt8(kp, 1.f));
            f[1] = __builtin_bit_cast(u32x4, cvt8(kp + 32, 1.f));
            f[2] = __builtin_bit_cast(u32x4, cvt8(kp + 4 * D_, 1.f));
            f[3] = __builtin_bit_cast(u32x4, cvt8(kp + 4 * D_ + 32, 1.f));
#pragma unroll
            for (int vb = 0; vb < 4; vb++) {
                bf16x8 vf;
#pragma unroll
                for (int j = 0; j < 8; j++)
                    vf[j] = (__bf16)Vf[(size_t)(kb + quad * 8 + j) * V_ + vb * 16 + l16];
                f[4 + vb] = __builtin_bit_cast(u32x4, vf);
            }
            computeChunk(f, kb, masked, false);
        };
        for (int c = w; c < nFull; c += NW) computeNW(c * CK, false);
        if (nPC > nFull && (nFull & (NW - 1)) == w) computeNW(nFull * CK, true);
        if (dc >= nPC && (dc & (NW - 1)) == w) computeNW(dc * CK, true);
    }

    // stash per-wave partials (l reduced across quads once, here)
#pragma unroll
    for (int vb = 0; vb < 4; vb++)
#pragma unroll
        for (int r = 0; r < 4; r++)
            obuf[w][l16][vb * 16 + quad * 4 + r] = oacc[vb][r];
    l_r += __shfl_xor(l_r, 16, 64);
    l_r += __shfl_xor(l_r, 32, 64);
    if (quad == 0) lbuf[w][l16] = l_r;
    __syncthreads();

    // merge 4 K-split partials: plain sums (shared fixed exponent); fp32 out
    const int row = tid >> 4;          // 0..15
    const int vd0 = (tid & 15) * 4;    // 0..60
    float lg = (lbuf[0][row] + lbuf[1][row]) + (lbuf[2][row] + lbuf[3][row]);
    float acc[4] = {0.f, 0.f, 0.f, 0.f};
#pragma unroll
    for (int ww = 0; ww < NW; ww++) {
#pragma unroll
        for (int i = 0; i < 4; i++) acc[i] += obuf[ww][row][vd0 + i];
    }
    const float inv = 1.f / lg;        // lg > 0: diagonal key never masked
    f32x4 o4 = (f32x4){acc[0] * inv, acc[1] * inv, acc[2] * inv, acc[3] * inv};
    *reinterpret_cast<f32x4*>(outm + ((size_t)(n * S_ + q0 + row)) * V_ + vd0) = o4;
}

extern "C" void kernel_launch(void* const* d_in, const int* in_sizes, int n_in,
                              void* d_out, int out_size, void* d_ws, size_t ws_size,
                              hipStream_t stream) {
    const float* Qf = (const float*)d_in[0];
    const float* Kf = (const float*)d_in[1];
    const float* Vf = (const float*)d_in[2];
    const int* plen = (const int*)d_in[3];
    float* outm = (float*)d_out;

    constexpr size_t ELEMS = (size_t)N_ * S_ * D_;        // 2^20
    const size_t need = 3 * ELEMS * sizeof(ushort);       // Qb + Kb + VT = 6 MB
    dim3 agrid(S_ / TQ, N_);                              // 128 x 8, n spread over XCDs

    if (ws_size >= need) {
        ushort* Qb  = (ushort*)d_ws;
        ushort* Kb  = Qb + ELEMS;
        ushort* VTb = Kb + ELEMS;
        prep_kernel<<<ELEMS / (256 * 4), 256, 0, stream>>>(Qf, Kf, Vf, Qb, Kb, VTb);
        attn_kernel<true><<<agrid, 256, 0, stream>>>(Qb, Kb, nullptr, VTb, plen, outm);
    } else {
        attn_kernel<false><<<agrid, 256, 0, stream>>>(Qf, Kf, Vf, nullptr, plen, outm);
    }
}

// Round 10
// 92.256 us; speedup vs baseline: 1.1277x; 1.1277x over previous
//
#include <hip/hip_runtime.h>
#include <cstdint>
#include <cstddef>

typedef __attribute__((ext_vector_type(8))) __bf16 bf16x8;
typedef __attribute__((ext_vector_type(2))) __bf16 bf16x2;
typedef __attribute__((ext_vector_type(4))) float f32x4;
typedef __attribute__((ext_vector_type(4))) unsigned int u32x4;

#define LOG2E 1.44269504088896340736f

constexpr int N_ = 8;
constexpr int S_ = 2048;
constexpr int D_ = 64;
constexpr int V_ = 64;
constexpr int TQ = 32;     // queries per task (two 16-row MFMA tiles share K/V)
constexpr int CK = 64;     // keys per chunk (two 32-key MFMA K-steps)
constexpr int NW = 8;      // waves per block (8-way K-split)
constexpr int NTASK = (S_ / TQ) * N_;   // 512 (n, q-tile) tasks

// Opaque 16B global load, SGPR base + 32-bit VGPR offset.
// NOTE: offset imm is 13-bit SIGNED -> must stay in [-4096, 4095].
#define GLDS(d, off, base, OFF) \
    asm volatile("global_load_dwordx4 %0, %1, %2 offset:" OFF \
                 : "=&v"(d) : "v"(off), "s"(base))
// Counted VMEM wait + scheduler fence (rule #18: reg-only MFMA can be hoisted
// past an asm waitcnt unless a sched_barrier follows).
#define WAITV(N) do { asm volatile("s_waitcnt vmcnt(" #N ")" ::: "memory"); \
                      __builtin_amdgcn_sched_barrier(0); } while (0)

__device__ __forceinline__ ushort f2bf(float x) {      // fp32 -> bf16 RNE
    uint u = __builtin_bit_cast(uint, x);
    return (ushort)((u + 0x7FFFu + ((u >> 16) & 1u)) >> 16);
}
__device__ __forceinline__ bf16x8 bc8(const u32x4& q) {
    return __builtin_bit_cast(bf16x8, q);
}
__device__ __forceinline__ bf16x8 cvt8(const float* p, float sc) {
    f32x4 a = *reinterpret_cast<const f32x4*>(p);
    f32x4 b = *reinterpret_cast<const f32x4*>(p + 4);
    bf16x8 r;
#pragma unroll
    for (int j = 0; j < 4; j++) { r[j] = (__bf16)(a[j] * sc); r[j + 4] = (__bf16)(b[j] * sc); }
    return r;
}
__device__ __forceinline__ uint pk2(float lo, float hi) {   // 2xf32 -> packed bf16x2
    bf16x2 t; t[0] = (__bf16)lo; t[1] = (__bf16)hi;
    return __builtin_bit_cast(uint, t);
}

// prefix_len dtype sniff (int64 iff hi-words all zero; values < 2048).
__device__ __forceinline__ int load_prefix(const int* plen, int n) {
    bool is64 = ((plen[1] | plen[3] | plen[5] | plen[7]) == 0);
    return is64 ? plen[2 * n] : plen[n];
}

// fp32 Q/K/V -> bf16. Qb pre-scaled by 0.125*LOG2E (exp2-domain scores).
// VT[n][s>>5][v][s&31]: V transposed, tiled by 32-key subtile so each
// subtile's 4 V loads fit signed-13-bit asm immediates {0..3072}.
// Block 0 additionally builds the balance schedule: n sorted by prefix DESC,
// sched[t] = (n_sorted[t>>6] << 16) | (t & 63). attn block b runs tasks
// sched[b] and sched[NTASK-1-b] (rank-complementary pairing -> per-CU work
// ~= p_heavy + p_light ~= const; R6's arbitrary pairing cost ~1.7x mean).
__global__ void prep_kernel(const float* __restrict__ Q, const float* __restrict__ K,
                            const float* __restrict__ V, ushort* __restrict__ Qb,
                            ushort* __restrict__ Kb, ushort* __restrict__ VTb,
                            const int* __restrict__ plen, int* __restrict__ sched) {
    const float QS = 0.125f * LOG2E;
    const int i4 = (blockIdx.x * 256 + threadIdx.x) * 4;   // over N*S*64 = 2^20 elems
    f32x4 q = *reinterpret_cast<const f32x4*>(Q + i4);
    f32x4 k = *reinterpret_cast<const f32x4*>(K + i4);
    f32x4 v = *reinterpret_cast<const f32x4*>(V + i4);
    ushort4 qo, ko;
    qo.x = f2bf(q[0] * QS); qo.y = f2bf(q[1] * QS); qo.z = f2bf(q[2] * QS); qo.w = f2bf(q[3] * QS);
    ko.x = f2bf(k[0]); ko.y = f2bf(k[1]); ko.z = f2bf(k[2]); ko.w = f2bf(k[3]);
    *reinterpret_cast<ushort4*>(Qb + i4) = qo;
    *reinterpret_cast<ushort4*>(Kb + i4) = ko;
    const int vd = i4 & (V_ - 1);
    const int s  = (i4 >> 6) & (S_ - 1);
    const int n  = i4 >> 17;
    const size_t base = ((size_t)n * 64 + (s >> 5)) * 2048 + (s & 31);
#pragma unroll
    for (int j = 0; j < 4; j++)
        VTb[base + (size_t)(vd + j) * 32] = f2bf(v[j]);

    if (blockIdx.x == 0) {
        __shared__ int ordl[8];
        if (threadIdx.x == 0) {
            int pv[8];
#pragma unroll
            for (int i = 0; i < 8; i++) { pv[i] = load_prefix(plen, i); ordl[i] = i; }
            for (int i = 1; i < 8; i++)
                for (int j = i; j > 0 && pv[ordl[j]] > pv[ordl[j - 1]]; j--) {
                    int t = ordl[j]; ordl[j] = ordl[j - 1]; ordl[j - 1] = t;
                }
        }
        __syncthreads();
        for (int t = threadIdx.x; t < NTASK; t += 256)
            sched[t] = (ordl[t >> 6] << 16) | (t & 63);
    }
}

// Swapped-QK flash attention. 256 blocks x 512 threads (1 block/CU, 8-wave
// K-split). Each block runs 2 prefix-balanced tasks from sched. Register
// double-buffered asm-load pipeline with split counted vmcnt waits:
// WAITV(24) K ready -> QK+exp; WAITV(16) V ready -> PV; refill; never 0 in
// the steady loop. Fixed-exponent softmax: p = 2^score unnormalized.
//   S^T = mfma(A=K_perm, B=Q): lane = query l16, keys quad*8..+7 (4 subtiles)
//   O^T = mfma(A=V^T, B=P^T): P lands in B-fragment order -> zero transpose.
template <bool WS>
__global__ __launch_bounds__(512, 2) void attn_kernel(
    const void* __restrict__ Qp, const void* __restrict__ Kp,
    const void* __restrict__ Vp, const ushort* __restrict__ VTb,
    const int* __restrict__ plen, const int* __restrict__ sched,
    float* __restrict__ outm)
{
    __shared__ float obuf[NW][TQ][V_ + 1];   // +1: merge-stage bank spread
    __shared__ float lbuf[NW][TQ];

    const int tid  = threadIdx.x;
    const int w    = tid >> 6;
    const int lane = tid & 63;
    const int quad = lane >> 4;
    const int l16  = lane & 15;
    // A-row permutation for QK: A row x holds key kb + 8*(x>>2) + (x&3)
    const int krow = ((l16 >> 2) << 3) + (l16 & 3);
    const uint vk0 = (uint)(krow * 128 + quad * 16);
    const uint vv0 = (uint)(l16 * 64 + quad * 16);

    const int nIt = WS ? 2 : 1;
    for (int it = 0; it < nIt; it++) {
        int n, q0;
        if (WS) {
            const int entry = sched[it == 0 ? (int)blockIdx.x
                                            : (NTASK - 1 - (int)blockIdx.x)];
            n  = entry >> 16;
            q0 = (entry & 0xffff) * TQ;
        } else {
            n  = blockIdx.y;
            q0 = blockIdx.x * TQ;
        }
        __syncthreads();                      // obuf/lbuf reuse across tasks

        const int prefix = load_prefix(plen, n);
        const int qrow0 = q0 + l16;
        const int qrow1 = q0 + 16 + l16;

        // Q B-fragments for both tiles: lane holds Q[qrow][quad*8 + (0..7)]
        bf16x8 qf00, qf01, qf10, qf11;
        if (WS) {
            const ushort* qptr = (const ushort*)Qp + ((size_t)(n * S_ + qrow0)) * D_ + quad * 8;
            uint4 u0 = *reinterpret_cast<const uint4*>(qptr);
            uint4 u1 = *reinterpret_cast<const uint4*>(qptr + 32);
            uint4 u2 = *reinterpret_cast<const uint4*>(qptr + 16 * D_);
            uint4 u3 = *reinterpret_cast<const uint4*>(qptr + 16 * D_ + 32);
            qf00 = __builtin_bit_cast(bf16x8, u0); qf01 = __builtin_bit_cast(bf16x8, u1);
            qf10 = __builtin_bit_cast(bf16x8, u2); qf11 = __builtin_bit_cast(bf16x8, u3);
        } else {
            const float* qptr = (const float*)Qp + ((size_t)(n * S_ + qrow0)) * D_ + quad * 8;
            qf00 = cvt8(qptr, 0.125f * LOG2E);            qf01 = cvt8(qptr + 32, 0.125f * LOG2E);
            qf10 = cvt8(qptr + 16 * D_, 0.125f * LOG2E);  qf11 = cvt8(qptr + 16 * D_ + 32, 0.125f * LOG2E);
        }
        // Materialize Q now: the compiler's vmcnt wait for these loads lands
        // HERE, before our asm prefetches -- keeps counted vmcnt exact.
        asm volatile("" : "+v"(qf00), "+v"(qf01), "+v"(qf10), "+v"(qf11));

        f32x4 oa[4], ob[4];
#pragma unroll
        for (int vb = 0; vb < 4; vb++) { oa[vb] = (f32x4){0.f,0.f,0.f,0.f}; ob[vb] = (f32x4){0.f,0.f,0.f,0.f}; }
        float l0 = 0.f, l1 = 0.f;

        const float* Kf = (const float*)Kp + (size_t)n * S_ * D_;
        const float* Vf = (const float*)Vp + (size_t)n * S_ * V_;
        // Uniform SGPR bases (per-n); sched came via scalar load so n is SGPR.
        const ushort* Kbb = (const ushort*)Kp + (size_t)n * S_ * D_;
        const ushort* VTn = VTb + (size_t)n * 64 * 2048;

        // Issue one chunk's 16 loads (K: 8, V: 8) into buffer f.
        // Two voffsets per stream keep every imm in {0..3072} (13-bit signed).
        auto issueKV = [&](u32x4* f, int c) {
            const uint ko  = vk0 + (uint)c * 8192u;   // 64 keys * 128 B
            const uint ko2 = ko + 4096u;              // keys +32
            const uint vo  = vv0 + (uint)c * 8192u;   // 2 subtiles * 4096 B
            const uint vo2 = vo + 4096u;
            GLDS(f[0],  ko,  Kbb, "0");    GLDS(f[1],  ko,  Kbb, "64");
            GLDS(f[2],  ko,  Kbb, "512");  GLDS(f[3],  ko,  Kbb, "576");
            GLDS(f[4],  ko2, Kbb, "0");    GLDS(f[5],  ko2, Kbb, "64");
            GLDS(f[6],  ko2, Kbb, "512");  GLDS(f[7],  ko2, Kbb, "576");
            GLDS(f[8],  vo,  VTn, "0");    GLDS(f[9],  vo,  VTn, "1024");
            GLDS(f[10], vo,  VTn, "2048"); GLDS(f[11], vo,  VTn, "3072");
            GLDS(f[12], vo2, VTn, "0");    GLDS(f[13], vo2, VTn, "1024");
            GLDS(f[14], vo2, VTn, "2048"); GLDS(f[15], vo2, VTn, "3072");
        };

        // Full chunk compute for both Q-tiles. If wait16: K already arrived
        // (WAITV(24) by caller); WAITV(16) just before PV (V arrival).
        auto computeChunk = [&](const u32x4* f, int kb, bool masked, bool wait16) {
            const f32x4 zero = (f32x4){0.f, 0.f, 0.f, 0.f};
            uint4 pw0, pw1, pw2, pw3;
            {   // ---- tile 0: QK + exp + pack ----
                f32x4 s0 = __builtin_amdgcn_mfma_f32_16x16x32_bf16(bc8(f[0]), qf00, zero, 0, 0, 0);
                s0 = __builtin_amdgcn_mfma_f32_16x16x32_bf16(bc8(f[1]), qf01, s0, 0, 0, 0);
                f32x4 s1 = __builtin_amdgcn_mfma_f32_16x16x32_bf16(bc8(f[2]), qf00, zero, 0, 0, 0);
                s1 = __builtin_amdgcn_mfma_f32_16x16x32_bf16(bc8(f[3]), qf01, s1, 0, 0, 0);
                f32x4 s2 = __builtin_amdgcn_mfma_f32_16x16x32_bf16(bc8(f[4]), qf00, zero, 0, 0, 0);
                s2 = __builtin_amdgcn_mfma_f32_16x16x32_bf16(bc8(f[5]), qf01, s2, 0, 0, 0);
                f32x4 s3 = __builtin_amdgcn_mfma_f32_16x16x32_bf16(bc8(f[6]), qf00, zero, 0, 0, 0);
                s3 = __builtin_amdgcn_mfma_f32_16x16x32_bf16(bc8(f[7]), qf01, s3, 0, 0, 0);
                if (masked) {
#pragma unroll
                    for (int r = 0; r < 4; r++) {
                        const int k0 = kb + 8 * quad + r;
                        s0[r] = (k0      < prefix || k0      == qrow0) ? s0[r] : -1e30f;
                        s1[r] = (k0 + 4  < prefix || k0 + 4  == qrow0) ? s1[r] : -1e30f;
                        s2[r] = (k0 + 32 < prefix || k0 + 32 == qrow0) ? s2[r] : -1e30f;
                        s3[r] = (k0 + 36 < prefix || k0 + 36 == qrow0) ? s3[r] : -1e30f;
                    }
                }
                float p0[4], p1[4], p2[4], p3[4];
#pragma unroll
                for (int r = 0; r < 4; r++) {
                    p0[r] = __builtin_amdgcn_exp2f(s0[r]);
                    p1[r] = __builtin_amdgcn_exp2f(s1[r]);
                    p2[r] = __builtin_amdgcn_exp2f(s2[r]);
                    p3[r] = __builtin_amdgcn_exp2f(s3[r]);
                }
                l0 += ((p0[0]+p0[1])+(p0[2]+p0[3])) + ((p1[0]+p1[1])+(p1[2]+p1[3]))
                    + ((p2[0]+p2[1])+(p2[2]+p2[3])) + ((p3[0]+p3[1])+(p3[2]+p3[3]));
                pw0.x = pk2(p0[0], p0[1]); pw0.y = pk2(p0[2], p0[3]);
                pw0.z = pk2(p1[0], p1[1]); pw0.w = pk2(p1[2], p1[3]);
                pw1.x = pk2(p2[0], p2[1]); pw1.y = pk2(p2[2], p2[3]);
                pw1.z = pk2(p3[0], p3[1]); pw1.w = pk2(p3[2], p3[3]);
            }
            {   // ---- tile 1: QK + exp + pack (scratch reused) ----
                f32x4 s0 = __builtin_amdgcn_mfma_f32_16x16x32_bf16(bc8(f[0]), qf10, zero, 0, 0, 0);
                s0 = __builtin_amdgcn_mfma_f32_16x16x32_bf16(bc8(f[1]), qf11, s0, 0, 0, 0);
                f32x4 s1 = __builtin_amdgcn_mfma_f32_16x16x32_bf16(bc8(f[2]), qf10, zero, 0, 0, 0);
                s1 = __builtin_amdgcn_mfma_f32_16x16x32_bf16(bc8(f[3]), qf11, s1, 0, 0, 0);
                f32x4 s2 = __builtin_amdgcn_mfma_f32_16x16x32_bf16(bc8(f[4]), qf10, zero, 0, 0, 0);
                s2 = __builtin_amdgcn_mfma_f32_16x16x32_bf16(bc8(f[5]), qf11, s2, 0, 0, 0);
                f32x4 s3 = __builtin_amdgcn_mfma_f32_16x16x32_bf16(bc8(f[6]), qf10, zero, 0, 0, 0);
                s3 = __builtin_amdgcn_mfma_f32_16x16x32_bf16(bc8(f[7]), qf11, s3, 0, 0, 0);
                if (masked) {
#pragma unroll
                    for (int r = 0; r < 4; r++) {
                        const int k0 = kb + 8 * quad + r;
                        s0[r] = (k0      < prefix || k0      == qrow1) ? s0[r] : -1e30f;
                        s1[r] = (k0 + 4  < prefix || k0 + 4  == qrow1) ? s1[r] : -1e30f;
                        s2[r] = (k0 + 32 < prefix || k0 + 32 == qrow1) ? s2[r] : -1e30f;
                        s3[r] = (k0 + 36 < prefix || k0 + 36 == qrow1) ? s3[r] : -1e30f;
                    }
                }
                float p0[4], p1[4], p2[4], p3[4];
#pragma unroll
                for (int r = 0; r < 4; r++) {
                    p0[r] = __builtin_amdgcn_exp2f(s0[r]);
                    p1[r] = __builtin_amdgcn_exp2f(s1[r]);
                    p2[r] = __builtin_amdgcn_exp2f(s2[r]);
                    p3[r] = __builtin_amdgcn_exp2f(s3[r]);
                }
                l1 += ((p0[0]+p0[1])+(p0[2]+p0[3])) + ((p1[0]+p1[1])+(p1[2]+p1[3]))
                    + ((p2[0]+p2[1])+(p2[2]+p2[3])) + ((p3[0]+p3[1])+(p3[2]+p3[3]));
                pw2.x = pk2(p0[0], p0[1]); pw2.y = pk2(p0[2], p0[3]);
                pw2.z = pk2(p1[0], p1[1]); pw2.w = pk2(p1[2], p1[3]);
                pw3.x = pk2(p2[0], p2[1]); pw3.y = pk2(p2[2], p2[3]);
                pw3.z = pk2(p3[0], p3[1]); pw3.w = pk2(p3[2], p3[3]);
            }
            if (wait16) WAITV(16);                   // V arrived (next chunk in flight)
            const bf16x8 pA0 = __builtin_bit_cast(bf16x8, pw0);
            const bf16x8 pA1 = __builtin_bit_cast(bf16x8, pw1);
            const bf16x8 pB0 = __builtin_bit_cast(bf16x8, pw2);
            const bf16x8 pB1 = __builtin_bit_cast(bf16x8, pw3);
#pragma unroll
            for (int vb = 0; vb < 4; vb++) {
                oa[vb] = __builtin_amdgcn_mfma_f32_16x16x32_bf16(bc8(f[8 + vb]),  pA0, oa[vb], 0, 0, 0);
                oa[vb] = __builtin_amdgcn_mfma_f32_16x16x32_bf16(bc8(f[12 + vb]), pA1, oa[vb], 0, 0, 0);
                ob[vb] = __builtin_amdgcn_mfma_f32_16x16x32_bf16(bc8(f[8 + vb]),  pB0, ob[vb], 0, 0, 0);
                ob[vb] = __builtin_amdgcn_mfma_f32_16x16x32_bf16(bc8(f[12 + vb]), pB1, ob[vb], 0, 0, 0);
            }
        };

        const int nFull = prefix >> 6;               // fully-valid 64-key chunks
        const int nPC   = (prefix + CK - 1) >> 6;
        const int dc    = q0 >> 6;                   // chunk holding the diagonal

        if (WS) {
            u32x4 bufA[16], bufB[16];
            int c = w;
            if (c < nFull) {
                issueKV(bufA, c);
                int c1 = c + NW;
                if (c1 >= nFull) {
                    WAITV(0); computeChunk(bufA, c * CK, false, false);
                } else {
                    issueKV(bufB, c1);
                    for (;;) {
                        int c2 = c1 + NW;
                        if (c2 >= nFull) {
                            WAITV(16); computeChunk(bufA, c * CK, false, false);
                            WAITV(0);  computeChunk(bufB, c1 * CK, false, false);
                            break;
                        }
                        WAITV(24);                                  // A.K arrived
                        computeChunk(bufA, c * CK, false, true);    // QK..WAITV(16)..PV
                        issueKV(bufA, c2);                          // refill A
                        c = c1; c1 = c2; c2 = c1 + NW;
                        if (c2 >= nFull) {
                            WAITV(16); computeChunk(bufB, c * CK, false, false);
                            WAITV(0);  computeChunk(bufA, c1 * CK, false, false);
                            break;
                        }
                        WAITV(24);                                  // B.K arrived
                        computeChunk(bufB, c * CK, false, true);
                        issueKV(bufB, c2);                          // refill B
                        c = c1; c1 = c2;
                    }
                }
            }
            if (nPC > nFull && (nFull & (NW - 1)) == w) {   // masked boundary
                issueKV(bufA, nFull); WAITV(0); computeChunk(bufA, nFull * CK, true, false);
            }
            if (dc >= nPC && (dc & (NW - 1)) == w) {        // pure diagonal
                issueKV(bufA, dc); WAITV(0); computeChunk(bufA, dc * CK, true, false);
            }
        } else {
            // fallback (fp32 inputs): unpipelined, converts in-flight
            auto computeNW = [&](int kb, bool masked) {
                u32x4 f[16];
                const float* kp = Kf + (size_t)(kb + krow) * D_ + quad * 8;
                f[0] = __builtin_bit_cast(u32x4, cvt8(kp, 1.f));
                f[1] = __builtin_bit_cast(u32x4, cvt8(kp + 32, 1.f));
                f[2] = __builtin_bit_cast(u32x4, cvt8(kp + 4 * D_, 1.f));
                f[3] = __builtin_bit_cast(u32x4, cvt8(kp + 4 * D_ + 32, 1.f));
                f[4] = __builtin_bit_cast(u32x4, cvt8(kp + 32 * D_, 1.f));
                f[5] = __builtin_bit_cast(u32x4, cvt8(kp + 32 * D_ + 32, 1.f));
                f[6] = __builtin_bit_cast(u32x4, cvt8(kp + 36 * D_, 1.f));
                f[7] = __builtin_bit_cast(u32x4, cvt8(kp + 36 * D_ + 32, 1.f));
#pragma unroll
                for (int vb = 0; vb < 4; vb++) {
                    bf16x8 vf0, vf1;
#pragma unroll
                    for (int j = 0; j < 8; j++) {
                        vf0[j] = (__bf16)Vf[(size_t)(kb + quad * 8 + j) * V_ + vb * 16 + l16];
                        vf1[j] = (__bf16)Vf[(size_t)(kb + 32 + quad * 8 + j) * V_ + vb * 16 + l16];
                    }
                    f[8 + vb]  = __builtin_bit_cast(u32x4, vf0);
                    f[12 + vb] = __builtin_bit_cast(u32x4, vf1);
                }
                computeChunk(f, kb, masked, false);
            };
            for (int c = w; c < nFull; c += NW) computeNW(c * CK, false);
            if (nPC > nFull && (nFull & (NW - 1)) == w) computeNW(nFull * CK, true);
            if (dc >= nPC && (dc & (NW - 1)) == w) computeNW(dc * CK, true);
        }

        // stash per-wave partials (l reduced across quads once, here)
#pragma unroll
        for (int vb = 0; vb < 4; vb++)
#pragma unroll
            for (int r = 0; r < 4; r++) {
                obuf[w][l16][vb * 16 + quad * 4 + r]      = oa[vb][r];
                obuf[w][16 + l16][vb * 16 + quad * 4 + r] = ob[vb][r];
            }
        l0 += __shfl_xor(l0, 16, 64);
        l0 += __shfl_xor(l0, 32, 64);
        l1 += __shfl_xor(l1, 16, 64);
        l1 += __shfl_xor(l1, 32, 64);
        if (quad == 0) { lbuf[w][l16] = l0; lbuf[w][16 + l16] = l1; }
        __syncthreads();

        // merge 8 K-split partials: plain sums (shared fixed exponent)
        const int row = tid >> 4;          // 0..31
        const int vd0 = (tid & 15) * 4;    // 0..60
        float lg = 0.f;
        float acc[4] = {0.f, 0.f, 0.f, 0.f};
#pragma unroll
        for (int ww = 0; ww < NW; ww++) {
            lg += lbuf[ww][row];
#pragma unroll
            for (int i = 0; i < 4; i++) acc[i] += obuf[ww][row][vd0 + i];
        }
        const float inv = 1.f / lg;        // lg > 0: diagonal key never masked
        f32x4 o4 = (f32x4){acc[0] * inv, acc[1] * inv, acc[2] * inv, acc[3] * inv};
        *reinterpret_cast<f32x4*>(outm + ((size_t)(n * S_ + q0 + row)) * V_ + vd0) = o4;
    }
}

extern "C" void kernel_launch(void* const* d_in, const int* in_sizes, int n_in,
                              void* d_out, int out_size, void* d_ws, size_t ws_size,
                              hipStream_t stream) {
    const float* Qf = (const float*)d_in[0];
    const float* Kf = (const float*)d_in[1];
    const float* Vf = (const float*)d_in[2];
    const int* plen = (const int*)d_in[3];
    float* outm = (float*)d_out;

    constexpr size_t ELEMS = (size_t)N_ * S_ * D_;        // 2^20
    const size_t need = 3 * ELEMS * sizeof(ushort) + NTASK * sizeof(int);

    if (ws_size >= need) {
        ushort* Qb  = (ushort*)d_ws;
        ushort* Kb  = Qb + ELEMS;
        ushort* VTb = Kb + ELEMS;
        int*   sched = (int*)(VTb + ELEMS);
        prep_kernel<<<ELEMS / (256 * 4), 256, 0, stream>>>(Qf, Kf, Vf, Qb, Kb, VTb, plen, sched);
        attn_kernel<true><<<NTASK / 2, 512, 0, stream>>>(Qb, Kb, nullptr, VTb, plen, sched, outm);
    } else {
        attn_kernel<false><<<dim3(S_ / TQ, N_), 512, 0, stream>>>(Qf, Kf, Vf, nullptr, plen, nullptr, outm);
    }
}